// Round 4
// baseline (127.342 us; speedup 1.0000x reference)
//
#include <hip/hip_runtime.h>

// Deformable conv (K=3, stride=1, pad=1, dil=1), N=8, Cin=Cout=128, H=W=64.
// R4: barrier-free wave-autonomous deform_main. Each wave = 16 wo x 128 co strip;
//     A-frags bilinearly gathered straight into registers (lane (lm,lq) samples
//     position lm, channels 32*ct+8*lq..+7 -- exactly the MFMA A layout), B-frags
//     streamed from global (L1-resident 32KB/kk, all waves sweep kk in order).
//     No LDS, no __syncthreads, no bank conflicts. Grid 512 x 256thr.
// ws: xt (NHWC bf16) 8 MB at +0 ; wtf (frag-major bf16) 288 KB at +8388608.

#define H  64
#define W  64
#define CIN 128
#define COUT 128
#define NB 8
#define KK 9

typedef short bf16x8 __attribute__((ext_vector_type(8)));
typedef float f32x4  __attribute__((ext_vector_type(4)));

__device__ __forceinline__ unsigned short f2bf(float f) {
    unsigned u = __builtin_bit_cast(unsigned, f);
    u += 0x7FFFu + ((u >> 16) & 1u);          // round-nearest-even
    return (unsigned short)(u >> 16);
}
__device__ __forceinline__ float lo_f(unsigned u) { return __builtin_bit_cast(float, u << 16); }
__device__ __forceinline__ float hi_f(unsigned u) { return __builtin_bit_cast(float, u & 0xFFFF0000u); }

// Fused prep: all 512 blocks transpose x NCHW fp32 -> NHWC bf16 (one (n,y) row each);
// blocks 0..71 additionally build wtf frag-major: [kk][nt:8][ct:4][lane:64][j:8].
// B-frag mapping (verified R1-R3): co = 16*nt + (lane&15), c = 32*ct + 8*(lane>>4) + j.
__global__ void prep_all(const float* __restrict__ x, const float* __restrict__ w,
                         unsigned short* __restrict__ xt, unsigned short* __restrict__ wtf) {
    if (blockIdx.x < 72) {
        int id = blockIdx.x * 256 + threadIdx.x;   // 18432 ids
        int lane = id & 63;
        int ct = (id >> 6) & 3;
        int nt = (id >> 8) & 7;
        int kk = id >> 11;
        int co = nt * 16 + (lane & 15);
        int c0 = ct * 32 + (lane >> 4) * 8;
        unsigned short v[8];
        #pragma unroll
        for (int j = 0; j < 8; ++j)
            v[j] = f2bf(w[((size_t)co * CIN + c0 + j) * KK + kk]);
        *(uint4*)(wtf + (size_t)id * 8) = *(const uint4*)v;
    }
    __shared__ float tile[CIN][W + 1];
    int b = blockIdx.x;                 // n*64 + y
    int n = b >> 6, y = b & 63;
    int t = threadIdx.x;
    int l = t & 63, g = t >> 6;
    const float* src = x + ((size_t)n * CIN * H + y) * W;
    #pragma unroll
    for (int i = 0; i < 32; ++i) {
        int c = g * 32 + i;
        tile[c][l] = src[(size_t)c * H * W + l];   // coalesced 256B row per wave
    }
    __syncthreads();
    int xp = t & 63;                    // lane-major x => conflict-free LDS reads
    int cb = (t >> 6) * 32;
    unsigned short* dst = xt + (((size_t)(n * H + y) * W + xp) * CIN + cb);
    unsigned rr[16];
    #pragma unroll
    for (int i = 0; i < 16; ++i) {
        rr[i] = (unsigned)f2bf(tile[cb + 2 * i][xp])
              | ((unsigned)f2bf(tile[cb + 2 * i + 1][xp]) << 16);
    }
    #pragma unroll
    for (int i = 0; i < 4; ++i)
        ((uint4*)dst)[i] = make_uint4(rr[4*i], rr[4*i+1], rr[4*i+2], rr[4*i+3]);
}

// Block = (n, ho), 256 threads = 4 independent waves. Wave wv: wo = wv*16..+15,
// all 128 co. No LDS, no barriers. acc 8 frags; 16 gather uint4 in flight per kk.
__global__ __launch_bounds__(256, 2) void deform_main(
        const float* __restrict__ offs, const unsigned short* __restrict__ xt,
        const unsigned short* __restrict__ wtf, float* __restrict__ out) {
    int b = blockIdx.x;
    int n = b >> 6, ho = b & 63;
    int t = threadIdx.x;
    int lane = t & 63, wv = t >> 6;
    int lm = lane & 15, lq = lane >> 4;
    int p = (wv << 4) + lm;              // this lane's sampled position (wo)
    int cb0 = lq << 3;                   // channel sub-base (k = 8*lq + j)

    const float* offp = offs + (((size_t)n * 2 * KK) * H + ho) * W + p;
    const unsigned short* xbase = xt + (size_t)n * H * W * CIN + cb0;

    f32x4 acc[8] = {};
    float dy = offp[0];
    float dx = offp[(size_t)H * W];
    int kh = 0, kw = 0;
    for (int kk = 0; kk < KK; ++kk) {
        // ---- bilinear setup for position p (same for the 4 lq-lanes; cheap) ----
        float py = (float)(ho - 1 + kh) + dy;
        float px = (float)(p  - 1 + kw) + dx;
        float y0f = floorf(py), x0f = floorf(px);
        float wy1 = py - y0f, wx1 = px - x0f;
        float wy0 = 1.f - wy1, wx0 = 1.f - wx1;
        int y0 = (int)y0f, x0 = (int)x0f;
        int y1 = y0 + 1, x1 = x0 + 1;
        bool vy0 = (unsigned)y0 < (unsigned)H, vy1 = (unsigned)y1 < (unsigned)H;
        bool vx0 = (unsigned)x0 < (unsigned)W, vx1 = (unsigned)x1 < (unsigned)W;
        float w00 = (vy0 && vx0) ? wy0 * wx0 : 0.f;
        float w01 = (vy0 && vx1) ? wy0 * wx1 : 0.f;
        float w10 = (vy1 && vx0) ? wy1 * wx0 : 0.f;
        float w11 = (vy1 && vx1) ? wy1 * wx1 : 0.f;
        int yc0 = min(max(y0, 0), H - 1), yc1 = min(max(y1, 0), H - 1);
        int xc0 = min(max(x0, 0), W - 1), xc1 = min(max(x1, 0), W - 1);
        const unsigned short* c00 = xbase + ((yc0 * W + xc0) << 7);
        const unsigned short* c01 = xbase + ((yc0 * W + xc1) << 7);
        const unsigned short* c10 = xbase + ((yc1 * W + xc0) << 7);
        const unsigned short* c11 = xbase + ((yc1 * W + xc1) << 7);
        // ---- issue ALL 16 corner gathers for this kk (latency amortized) ----
        uint4 q[4][4];
        #pragma unroll
        for (int ct = 0; ct < 4; ++ct) {
            q[ct][0] = *(const uint4*)(c00 + (ct << 5));
            q[ct][1] = *(const uint4*)(c01 + (ct << 5));
            q[ct][2] = *(const uint4*)(c10 + (ct << 5));
            q[ct][3] = *(const uint4*)(c11 + (ct << 5));
        }
        // prefetch next kk's offsets while gathers are in flight
        if (kk < KK - 1) {
            dy = offp[(size_t)(2 * kk + 2) * H * W];
            dx = offp[(size_t)(2 * kk + 3) * H * W];
        }
        ++kw; if (kw == 3) { kw = 0; ++kh; }
        const unsigned short* wk = wtf + (size_t)kk * 16384 + (lane << 3);
        // ---- blend -> A-frag in registers -> MFMA (B from global, L1-hot) ----
        #pragma unroll
        for (int ct = 0; ct < 4; ++ct) {
            const unsigned* a0 = (const unsigned*)&q[ct][0];
            const unsigned* a1 = (const unsigned*)&q[ct][1];
            const unsigned* a2 = (const unsigned*)&q[ct][2];
            const unsigned* a3 = (const unsigned*)&q[ct][3];
            unsigned rr[4];
            #pragma unroll
            for (int i = 0; i < 4; ++i) {
                float v0 = w00*lo_f(a0[i]) + w01*lo_f(a1[i]) + w10*lo_f(a2[i]) + w11*lo_f(a3[i]);
                float v1 = w00*hi_f(a0[i]) + w01*hi_f(a1[i]) + w10*hi_f(a2[i]) + w11*hi_f(a3[i]);
                rr[i] = (unsigned)f2bf(v0) | ((unsigned)f2bf(v1) << 16);
            }
            bf16x8 a = __builtin_bit_cast(bf16x8, *(uint4*)rr);
            #pragma unroll
            for (int nt = 0; nt < 8; ++nt) {
                bf16x8 bf = *(const bf16x8*)(wk + (((nt << 2) + ct) << 9));
                acc[nt] = __builtin_amdgcn_mfma_f32_16x16x32_bf16(a, bf, acc[nt], 0, 0, 0);
            }
        }
    }
    // epilogue: D[m=4*lq+r][nn=lm] -> wo = wv*16 + 4*lq + r, co = nt*16 + lm
    int wo = (wv << 4) + (lq << 2);
    #pragma unroll
    for (int nt = 0; nt < 8; ++nt) {
        int co = (nt << 4) + lm;
        *(f32x4*)(out + (((size_t)(n * COUT + co) * H + ho) * W + wo)) = acc[nt];
    }
}

extern "C" void kernel_launch(void* const* d_in, const int* in_sizes, int n_in,
                              void* d_out, int out_size, void* d_ws, size_t ws_size,
                              hipStream_t stream) {
    const float* x      = (const float*)d_in[0];   // (8,128,64,64)
    const float* offset = (const float*)d_in[1];   // (8,18,64,64)
    const float* weight = (const float*)d_in[2];   // (128,128,3,3)
    float* out = (float*)d_out;

    unsigned short* xt  = (unsigned short*)d_ws;                                  // 8 MB
    unsigned short* wtf = (unsigned short*)((char*)d_ws + (size_t)NB*H*W*CIN*2);  // 288 KB

    hipLaunchKernelGGL(prep_all, dim3(NB * H), dim3(256), 0, stream, x, weight, xt, wtf);
    hipLaunchKernelGGL(deform_main, dim3(NB * H), dim3(256), 0, stream,
                       offset, xt, wtf, out);
}